// Round 1
// baseline (10967.589 us; speedup 1.0000x reference)
//
#include <hip/hip_runtime.h>

#define BDIM 64
#define TDIM 1024
#define DDIM 256
#define HDIM 512
#define RING 8

typedef unsigned short ushort_t;
typedef unsigned int uint32;
typedef __attribute__((ext_vector_type(8))) short short8;
typedef __attribute__((ext_vector_type(4))) float f32x4;

__device__ __forceinline__ ushort_t f2bf(float f) {
  union { float f; uint32 u; } v; v.f = f;
  uint32 u = v.u;
  uint32 r = (u + 0x7fffu + ((u >> 16) & 1u)) >> 16;
  return (ushort_t)r;
}

__device__ __forceinline__ short8 pack8(float4 a, float4 b) {
  short8 s;
  s[0] = (short)f2bf(a.x); s[1] = (short)f2bf(a.y);
  s[2] = (short)f2bf(a.z); s[3] = (short)f2bf(a.w);
  s[4] = (short)f2bf(b.x); s[5] = (short)f2bf(b.y);
  s[6] = (short)f2bf(b.z); s[7] = (short)f2bf(b.w);
  return s;
}

__device__ __forceinline__ float sigm(float x) { return 1.0f / (1.0f + __expf(-x)); }
__device__ __forceinline__ float tanh_fast(float x) { return 1.0f - 2.0f / (__expf(2.0f * x) + 1.0f); }

__device__ __forceinline__ void spin32(uint32* p) {
  int it = 0;
  while (__hip_atomic_load(p, __ATOMIC_RELAXED, __HIP_MEMORY_SCOPE_AGENT) < 32u) {
    __builtin_amdgcn_s_sleep(1);
    if (++it > 20000000) break;   // safety bailout: wrong answer beats a hang
  }
}

__global__ void __launch_bounds__(256, 1)
lstm_fused(const float* __restrict__ x,
           const float* __restrict__ w_ih0, const float* __restrict__ w_hh0,
           const float* __restrict__ b0,
           const float* __restrict__ w_ih1, const float* __restrict__ w_hh1,
           const float* __restrict__ b1,
           float* __restrict__ out,
           uint32* cnt0, uint32* cnt1, uint32* ccnt,
           ushort_t* ring, ushort_t* h1buf)
{
  const int layer = (int)(blockIdx.x >> 7);
  const int bid   = (int)(blockIdx.x & 127);
  const int bt    = bid >> 5;     // batch tile 0..3 (16 rows)
  const int ct    = bid & 31;     // hcol tile 0..31 (16 cols)
  const int tid   = (int)threadIdx.x;
  const int wv    = tid >> 6;     // wave = gate type: 0=i 1=f 2=o 3=g
  const int lane  = tid & 63;
  const int lr    = lane & 15;
  const int lg    = lane >> 4;

  __shared__ ushort_t As[16 * 1024];   // A tile [16 rows][K up to 1024], XOR-swizzled
  __shared__ float gates[4][16][16];   // [gate][batch r][col j]

  const int NFX = layer ? 16 : 8;      // K-fragments of input part
  const int NF  = layer ? 32 : 24;     // total K-fragments
  const int Din = layer ? HDIM : DDIM;
  const float* wih = layer ? w_ih1 : w_ih0;
  const float* whh = layer ? w_hh1 : w_hh0;
  const float* bb  = layer ? b1 : b0;

  const int grow = wv * HDIM + ct * 16 + lr;   // gate row this lane's B-col maps to

  // ---- load weight fragments into registers (one-time) ----
  short8 wf[32];
#pragma unroll
  for (int kf = 0; kf < 32; ++kf) wf[kf] = (short8)((short)0);
#pragma unroll
  for (int kf = 0; kf < 32; ++kf) {
    if (kf < NF) {
      const float* src;
      if (kf < NFX) src = wih + (size_t)grow * Din + (size_t)kf * 32 + lg * 8;
      else          src = whh + (size_t)grow * HDIM + (size_t)(kf - NFX) * 32 + lg * 8;
      float4 a = *(const float4*)(src);
      float4 b = *(const float4*)(src + 4);
      wf[kf] = pack8(a, b);
    }
  }
  const float bias = bb[grow];

  // pointwise ownership: thread -> (batch row pr, col pj)
  const int pr = tid >> 4, pj = tid & 15;
  const int pb = bt * 16 + pr;
  const int pcol = ct * 16 + pj;
  float c_state = 0.0f;

  uint32* my   = (layer ? cnt1 : cnt0) + bt * 1024;
  uint32* dep0 = cnt0 + bt * 1024;
  uint32* cc   = ccnt + bt * 1024;

  for (int t = 0; t < TDIM; ++t) {
    // ---- waits ----
    if (tid == 0) {
      if (layer == 0) {
        if (t > 0)     spin32(&my[t - 1]);       // own h0[t-1] complete (all 32 col-blocks)
        if (t >= RING) spin32(&cc[t - RING]);    // ring slot consumed by layer 1
      } else {
        spin32(&dep0[t]);                        // y0[t] ready
        if (t > 0) spin32(&my[t - 1]);           // h1[t-1] complete
      }
      __builtin_amdgcn_fence(__ATOMIC_ACQUIRE, "agent");
    }
    __syncthreads();

    // ---- stage A tile into LDS (bf16, swizzled) ----
    if (layer == 0) {
      {
        const int r2 = tid >> 4;
        const int c0v = (tid & 15) * 16;
        const float* xs = x + (size_t)(bt * 16 + r2) * (TDIM * DDIM) + (size_t)t * DDIM + c0v;
        const float4* xv = (const float4*)xs;
        float4 a0 = xv[0], a1 = xv[1], a2 = xv[2], a3 = xv[3];
        const int sw = (r2 & 7) << 3;
        *(short8*)&As[(r2 * 1024 + c0v) ^ sw]     = pack8(a0, a1);
        *(short8*)&As[(r2 * 1024 + c0v + 8) ^ sw] = pack8(a2, a3);
      }
      if (t > 0) {
        const ushort_t* hsrc = ring + (size_t)((t - 1) & (RING - 1)) * (BDIM * HDIM)
                                    + (size_t)bt * 16 * HDIM;
#pragma unroll
        for (int q = 0; q < 4; ++q) {
          int lin = tid * 32 + q * 8;
          int r2 = lin >> 9, k = lin & 511;
          short8 v = *(const short8*)&hsrc[lin];
          *(short8*)&As[(r2 * 1024 + 256 + k) ^ ((r2 & 7) << 3)] = v;
        }
      }
    } else {
      const ushort_t* ysrc = ring + (size_t)(t & (RING - 1)) * (BDIM * HDIM)
                                  + (size_t)bt * 16 * HDIM;
#pragma unroll
      for (int q = 0; q < 4; ++q) {
        int lin = tid * 32 + q * 8;
        int r2 = lin >> 9, k = lin & 511;
        short8 v = *(const short8*)&ysrc[lin];
        *(short8*)&As[(r2 * 1024 + k) ^ ((r2 & 7) << 3)] = v;
      }
      if (t > 0) {
        const ushort_t* hsrc = h1buf + (size_t)((t - 1) & 1) * (BDIM * HDIM)
                                     + (size_t)bt * 16 * HDIM;
#pragma unroll
        for (int q = 0; q < 4; ++q) {
          int lin = tid * 32 + q * 8;
          int r2 = lin >> 9, k = lin & 511;
          short8 v = *(const short8*)&hsrc[lin];
          *(short8*)&As[(r2 * 1024 + 512 + k) ^ ((r2 & 7) << 3)] = v;
        }
      }
    }
    __syncthreads();
    if (layer == 1 && tid == 0) {
      // y0[t] consumed into LDS (loads drained by barrier) -> release ring slot
      __hip_atomic_fetch_add(&cc[t], 1u, __ATOMIC_RELAXED, __HIP_MEMORY_SCOPE_AGENT);
    }

    // ---- MFMA: gates tile [16 batch x 16 cols] per wave ----
    const int kfmax = (t == 0) ? NFX : NF;   // t==0: h==0, skip hh part
    f32x4 acc0 = {0.f, 0.f, 0.f, 0.f}, acc1 = {0.f, 0.f, 0.f, 0.f};
    const int abase = lr * 1024 + lg * 8;
    const int asw = (lr & 7) << 3;
#pragma unroll
    for (int kf = 0; kf < 32; ++kf) {
      if (kf < kfmax) {
        const short8 af = *(const short8*)&As[(abase + kf * 32) ^ asw];
        if (kf & 1) acc1 = __builtin_amdgcn_mfma_f32_16x16x32_bf16(af, wf[kf], acc1, 0, 0, 0);
        else        acc0 = __builtin_amdgcn_mfma_f32_16x16x32_bf16(af, wf[kf], acc0, 0, 0, 0);
      }
    }
#pragma unroll
    for (int i = 0; i < 4; ++i) {
      float v = acc0[i] + acc1[i] + bias;
      float a = (wv < 3) ? sigm(v) : tanh_fast(v);
      gates[wv][lg * 4 + i][lr] = a;   // C/D: col=lane&15, row=(lane>>4)*4+reg
    }
    __syncthreads();

    // ---- pointwise LSTM cell ----
    {
      float gi = gates[0][pr][pj];
      float gf = gates[1][pr][pj];
      float go = gates[2][pr][pj];
      float gg = gates[3][pr][pj];
      float nc = gf * c_state + gi * gg;
      float nh = go * tanh_fast(nc);          // h uses UNCLIPPED c (matches ref)
      nc = fminf(fmaxf(nc, -50.f), 50.f);
      nh = fminf(fmaxf(nh, -50.f), 50.f);
      c_state = nc;
      ushort_t hb = f2bf(nh);
      if (layer == 0) {
        ring[(size_t)(t & (RING - 1)) * (BDIM * HDIM) + (size_t)pb * HDIM + pcol] = hb;
      } else {
        h1buf[(size_t)(t & 1) * (BDIM * HDIM) + (size_t)pb * HDIM + pcol] = hb;
        out[(size_t)pb * (TDIM * HDIM) + (size_t)t * HDIM + pcol] = nh;
      }
      if (t == TDIM - 1) {
        const size_t OH = (size_t)BDIM * TDIM * HDIM;
        const size_t OC = OH + 2 * (size_t)BDIM * HDIM;
        out[OH + (size_t)layer * BDIM * HDIM + (size_t)pb * HDIM + pcol] = nh;
        out[OC + (size_t)layer * BDIM * HDIM + (size_t)pb * HDIM + pcol] = nc;
      }
    }
    __syncthreads();   // drains all threads' stores (vmcnt 0) before publishing
    if (tid == 0) {
      __builtin_amdgcn_fence(__ATOMIC_RELEASE, "agent");
      __hip_atomic_fetch_add(&my[t], 1u, __ATOMIC_RELAXED, __HIP_MEMORY_SCOPE_AGENT);
    }
  }
}

extern "C" void kernel_launch(void* const* d_in, const int* in_sizes, int n_in,
                              void* d_out, int out_size, void* d_ws, size_t ws_size,
                              hipStream_t stream) {
  (void)in_sizes; (void)n_in; (void)out_size; (void)ws_size;
  const float* x     = (const float*)d_in[0];
  const float* w_ih0 = (const float*)d_in[1];
  const float* w_hh0 = (const float*)d_in[2];
  const float* b0    = (const float*)d_in[3];
  const float* w_ih1 = (const float*)d_in[4];
  const float* w_hh1 = (const float*)d_in[5];
  const float* b1    = (const float*)d_in[6];
  float* out = (float*)d_out;

  char* ws = (char*)d_ws;
  uint32* cnt0 = (uint32*)ws;                       // [4][1024]
  uint32* cnt1 = cnt0 + 4 * 1024;                   // [4][1024]
  uint32* ccnt = cnt1 + 4 * 1024;                   // [4][1024]
  ushort_t* ring  = (ushort_t*)(ws + 48 * 1024);            // [8][64][512] bf16
  ushort_t* h1buf = (ushort_t*)(ws + 48 * 1024 + 512 * 1024); // [2][64][512] bf16

  hipMemsetAsync(ws, 0, 48 * 1024, stream);
  lstm_fused<<<dim3(256), dim3(256), 0, stream>>>(
      x, w_ih0, w_hh0, b0, w_ih1, w_hh1, b1, out, cnt0, cnt1, ccnt, ring, h1buf);
}

// Round 2
// 4215.746 us; speedup vs baseline: 2.6016x; 2.6016x over previous
//
#include <hip/hip_runtime.h>

#define BDIM 64
#define TDIM 1024
#define DDIM 256
#define HDIM 512
#define RING 8

typedef unsigned short ushort_t;
typedef unsigned int uint32;
typedef unsigned long long ull;
typedef __attribute__((ext_vector_type(8))) short short8;
typedef __attribute__((ext_vector_type(4))) float f32x4;

__device__ __forceinline__ ushort_t f2bf(float f) {
  union { float f; uint32 u; } v; v.f = f;
  uint32 u = v.u;
  uint32 r = (u + 0x7fffu + ((u >> 16) & 1u)) >> 16;
  return (ushort_t)r;
}

__device__ __forceinline__ short8 pack8(float4 a, float4 b) {
  short8 s;
  s[0] = (short)f2bf(a.x); s[1] = (short)f2bf(a.y);
  s[2] = (short)f2bf(a.z); s[3] = (short)f2bf(a.w);
  s[4] = (short)f2bf(b.x); s[5] = (short)f2bf(b.y);
  s[6] = (short)f2bf(b.z); s[7] = (short)f2bf(b.w);
  return s;
}

__device__ __forceinline__ float sigm(float x) { return 1.0f / (1.0f + __expf(-x)); }
__device__ __forceinline__ float tanh_fast(float x) { return 1.0f - 2.0f / (__expf(2.0f * x) + 1.0f); }

// wave0-wide poll: each lane watches one flag word; exit when all >= tgt.
__device__ __forceinline__ void wave_poll(uint32* fl, uint32 tgt) {
  int it = 0;
  for (;;) {
    uint32 v = __hip_atomic_load(fl, __ATOMIC_RELAXED, __HIP_MEMORY_SCOPE_AGENT);
    if (__all((int)(v >= tgt))) break;
    __builtin_amdgcn_s_sleep(1);
    if (++it > 300000) break;   // safety bailout: wrong answer beats a hang
  }
  asm volatile("" ::: "memory");
}

// stage a 16x512 bf16 tile (producer wrote it sc1) into LDS region (stride 512,
// XOR-swizzled). Loads are issued back-to-back, then ds_writes drain them in
// order -> pipelined. Wave-contiguous writes: conflict-free.
__device__ __forceinline__ void stage16x512(const ull* src, ushort_t* dst, int tid) {
  ull v[8];
#pragma unroll
  for (int q = 0; q < 8; ++q)
    v[q] = __hip_atomic_load((ull*)(src + q * 256 + tid),
                             __ATOMIC_RELAXED, __HIP_MEMORY_SCOPE_AGENT);
#pragma unroll
  for (int q = 0; q < 8; ++q) {
    int idx = q * 256 + tid;
    int r = idx >> 7, inner = idx & 127;
    *(ull*)&dst[(r * 512 + inner * 4) ^ ((r & 7) << 3)] = v[q];
  }
}

__global__ void __launch_bounds__(256, 1)
lstm_fused(const float* __restrict__ x,
           const float* __restrict__ w_ih0, const float* __restrict__ w_hh0,
           const float* __restrict__ b0,
           const float* __restrict__ w_ih1, const float* __restrict__ w_hh1,
           const float* __restrict__ b1,
           float* __restrict__ out,
           uint32* cnt0F, uint32* cnt1F, uint32* consF,
           ushort_t* ring, ushort_t* h1buf)
{
  const int layer = (int)(blockIdx.x >> 7);
  const int bid   = (int)(blockIdx.x & 127);
  const int bt    = bid >> 5;     // batch tile 0..3 (16 rows)
  const int ct    = bid & 31;     // hcol tile 0..31 (16 cols)
  const int tid   = (int)threadIdx.x;
  const int wv    = tid >> 6;     // wave = gate type: 0=i 1=f 2=o 3=g
  const int lane  = tid & 63;
  const int lr    = lane & 15;
  const int lg    = lane >> 4;

  __shared__ __align__(16) ushort_t Is[16 * 512];  // input-part A tile (x or y0)
  __shared__ __align__(16) ushort_t Hs[16 * 512];  // recurrent-part A tile (h[t-1])
  __shared__ float gates[4][16][16];
  __shared__ __align__(16) ushort_t htmp[256];

  const int NI  = layer ? 16 : 8;      // K-fragments of input part
  const int Din = layer ? HDIM : DDIM;
  const float* wih = layer ? w_ih1 : w_ih0;
  const float* whh = layer ? w_hh1 : w_hh0;
  const float* bb  = layer ? b1 : b0;

  const int grow = wv * HDIM + ct * 16 + lr;   // gate row for this lane's B-col

  // ---- one-time: weights into registers ----
  short8 wf[32];
#pragma unroll
  for (int kf = 0; kf < 32; ++kf) wf[kf] = (short8)((short)0);
#pragma unroll
  for (int kf = 0; kf < 32; ++kf) {
    if (kf < NI + 16) {
      const float* src;
      if (kf < NI) src = wih + (size_t)grow * Din + (size_t)kf * 32 + lg * 8;
      else         src = whh + (size_t)grow * HDIM + (size_t)(kf - NI) * 32 + lg * 8;
      float4 a = *(const float4*)(src);
      float4 b = *(const float4*)(src + 4);
      wf[kf] = pack8(a, b);
    }
  }
  const float bias = bb[grow];

  // pointwise ownership
  const int pr = tid >> 4, pj = tid & 15;
  const int pb = bt * 16 + pr;
  const int pcol = ct * 16 + pj;
  float c_state = 0.0f;

  uint32* myflag = (layer ? cnt1F : cnt0F) + bt * 32 + ct;
  uint32* cons_mine = consF + bt * 32 + ct;
  const ull* ring_u = (const ull*)ring;
  const ull* h1_u   = (const ull*)h1buf;

  for (int t = 0; t < TDIM; ++t) {
    // ---- phase A: input-part staging + chain polls ----
    if (layer == 0) {
      {  // stage x[t] (no dependency, normal cached loads)
        const int r2  = tid >> 4;
        const int c0v = (tid & 15) * 16;
        const float4* xv = (const float4*)(x + (size_t)(bt * 16 + r2) * (TDIM * DDIM)
                                             + (size_t)t * DDIM + c0v);
        float4 a0 = xv[0], a1 = xv[1], a2 = xv[2], a3 = xv[3];
        const int sw = (r2 & 7) << 3;
        *(short8*)&Is[(r2 * 512 + c0v) ^ sw]     = pack8(a0, a1);
        *(short8*)&Is[(r2 * 512 + c0v + 8) ^ sw] = pack8(a2, a3);
      }
      if (wv == 0) {  // own h0-chain + ring credit
        uint32* fl; uint32 tgt;
        if (lane < 32) { fl = cnt0F + bt * 32 + lane; tgt = (uint32)t; }
        else { fl = consF + bt * 32 + (lane - 32); tgt = (t >= RING) ? (uint32)(t - RING + 1) : 0u; }
        wave_poll(fl, tgt);
      }
    } else {
      if (wv == 0) wave_poll(cnt0F + bt * 32 + (lane & 31), (uint32)(t + 1));  // y0[t] ready
      __syncthreads();
      stage16x512(ring_u + (size_t)(t & (RING - 1)) * 8192 + (size_t)bt * 2048, Is, tid);
      if (wv == 0) wave_poll(cnt1F + bt * 32 + (lane & 31), (uint32)t);        // own h1-chain
    }
    __syncthreads();
    if (layer == 1 && tid == 0)   // y0[t] captured in LDS -> release ring slot
      __hip_atomic_store(cons_mine, (uint32)(t + 1), __ATOMIC_RELAXED, __HIP_MEMORY_SCOPE_AGENT);

    // ---- phase B: stage h[t-1] ----
    if (t > 0) {
      const ull* src = (layer == 0)
          ? ring_u + (size_t)((t - 1) & (RING - 1)) * 8192 + (size_t)bt * 2048
          : h1_u   + (size_t)((t - 1) & 1) * 8192 + (size_t)bt * 2048;
      stage16x512(src, Hs, tid);
    }
    __syncthreads();

    // ---- phase C: MFMA gates tile [16 x 16] per wave ----
    const int kmax = (t == 0) ? NI : NI + 16;
    f32x4 acc0 = {0.f, 0.f, 0.f, 0.f}, acc1 = {0.f, 0.f, 0.f, 0.f};
    const int fb  = lr * 512 + lg * 8;
    const int fsw = (lr & 7) << 3;
#pragma unroll
    for (int kf = 0; kf < 32; ++kf) {
      if (kf < kmax) {
        const ushort_t* p = (kf < NI) ? &Is[(fb + kf * 32) ^ fsw]
                                      : &Hs[(fb + (kf - NI) * 32) ^ fsw];
        const short8 af = *(const short8*)p;
        if (kf & 1) acc1 = __builtin_amdgcn_mfma_f32_16x16x32_bf16(af, wf[kf], acc1, 0, 0, 0);
        else        acc0 = __builtin_amdgcn_mfma_f32_16x16x32_bf16(af, wf[kf], acc0, 0, 0, 0);
      }
    }
#pragma unroll
    for (int i = 0; i < 4; ++i) {
      float v = acc0[i] + acc1[i] + bias;
      float a = (wv < 3) ? sigm(v) : tanh_fast(v);
      gates[wv][lg * 4 + i][lr] = a;   // C/D: col=lane&15, row=(lane>>4)*4+reg
    }
    __syncthreads();

    // ---- phase D: pointwise LSTM cell ----
    {
      float gi = gates[0][pr][pj];
      float gf = gates[1][pr][pj];
      float go = gates[2][pr][pj];
      float gg = gates[3][pr][pj];
      float nc = gf * c_state + gi * gg;
      float nh = go * tanh_fast(nc);          // h uses UNCLIPPED c (matches ref)
      nc = fminf(fmaxf(nc, -50.f), 50.f);
      nh = fminf(fmaxf(nh, -50.f), 50.f);
      c_state = nc;
      htmp[pr * 16 + pj] = f2bf(nh);
      if (layer == 1) out[(size_t)pb * (TDIM * HDIM) + (size_t)t * HDIM + pcol] = nh;
      if (t == TDIM - 1) {
        const size_t OH = (size_t)BDIM * TDIM * HDIM;
        const size_t OC = OH + 2 * (size_t)BDIM * HDIM;
        out[OH + (size_t)layer * BDIM * HDIM + (size_t)pb * HDIM + pcol] = nh;
        out[OC + (size_t)layer * BDIM * HDIM + (size_t)pb * HDIM + pcol] = nc;
      }
    }
    __syncthreads();

    // ---- phase E: publish h tile (sc1) + flag ----
    if (tid < 64) {
      ull hv = ((ull*)htmp)[tid];
      const int r = tid >> 2, cu = tid & 3;
      ull* dst;
      if (layer == 0)
        dst = (ull*)ring  + (size_t)(t & (RING - 1)) * 8192 + (size_t)(bt * 16 + r) * 128 + ct * 4 + cu;
      else
        dst = (ull*)h1buf + (size_t)(t & 1) * 8192 + (size_t)(bt * 16 + r) * 128 + ct * 4 + cu;
      __hip_atomic_store(dst, hv, __ATOMIC_RELAXED, __HIP_MEMORY_SCOPE_AGENT);
    }
    asm volatile("s_waitcnt vmcnt(0)" ::: "memory");   // wave-local: h stores reached MALL
    if (tid == 0)
      __hip_atomic_store(myflag, (uint32)(t + 1), __ATOMIC_RELAXED, __HIP_MEMORY_SCOPE_AGENT);
  }
}

extern "C" void kernel_launch(void* const* d_in, const int* in_sizes, int n_in,
                              void* d_out, int out_size, void* d_ws, size_t ws_size,
                              hipStream_t stream) {
  (void)in_sizes; (void)n_in; (void)out_size; (void)ws_size;
  const float* x     = (const float*)d_in[0];
  const float* w_ih0 = (const float*)d_in[1];
  const float* w_hh0 = (const float*)d_in[2];
  const float* b0    = (const float*)d_in[3];
  const float* w_ih1 = (const float*)d_in[4];
  const float* w_hh1 = (const float*)d_in[5];
  const float* b1    = (const float*)d_in[6];
  float* out = (float*)d_out;

  char* ws = (char*)d_ws;
  uint32* cnt0F = (uint32*)ws;               // [4][32] monotonic step flags, layer 0
  uint32* cnt1F = (uint32*)(ws + 512);       // [4][32] layer 1
  uint32* consF = (uint32*)(ws + 1024);      // [4][32] ring-consumption flags
  ushort_t* ring  = (ushort_t*)(ws + 48 * 1024);                 // [8][64][512] bf16
  ushort_t* h1buf = (ushort_t*)(ws + 48 * 1024 + 512 * 1024);    // [2][64][512] bf16

  hipMemsetAsync(ws, 0, 4096, stream);
  lstm_fused<<<dim3(256), dim3(256), 0, stream>>>(
      x, w_ih0, w_hh0, b0, w_ih1, w_hh1, b1, out, cnt0F, cnt1F, consF, ring, h1buf);
}

// Round 4
// 3968.207 us; speedup vs baseline: 2.7639x; 1.0624x over previous
//
#include <hip/hip_runtime.h>

#define BDIM 64
#define TDIM 1024
#define DDIM 256
#define HDIM 512
#define RING 8

typedef unsigned short ushort_t;
typedef unsigned int uint32;
typedef unsigned long long ull;
typedef __attribute__((ext_vector_type(8))) short short8;
typedef __attribute__((ext_vector_type(4))) float f32x4;

__device__ __forceinline__ ushort_t f2bf(float f) {
  union { float f; uint32 u; } v; v.f = f;
  uint32 u = v.u;
  return (ushort_t)((u + 0x7fffu + ((u >> 16) & 1u)) >> 16);
}

__device__ __forceinline__ short8 pack8(float4 a, float4 b) {
  short8 s;
  s[0] = (short)f2bf(a.x); s[1] = (short)f2bf(a.y);
  s[2] = (short)f2bf(a.z); s[3] = (short)f2bf(a.w);
  s[4] = (short)f2bf(b.x); s[5] = (short)f2bf(b.y);
  s[6] = (short)f2bf(b.z); s[7] = (short)f2bf(b.w);
  return s;
}

__device__ __forceinline__ ull pack4bf(f32x4 v) {
  return (ull)f2bf(v[0]) | ((ull)f2bf(v[1]) << 16)
       | ((ull)f2bf(v[2]) << 32) | ((ull)f2bf(v[3]) << 48);
}

__device__ __forceinline__ float sigm(float x) { return 1.0f / (1.0f + __expf(-x)); }
__device__ __forceinline__ float tanh_fast(float x) { return 1.0f - 2.0f / (__expf(2.0f * x) + 1.0f); }

__device__ __forceinline__ uint32 ld_sc1(uint32* p) {
  return __hip_atomic_load(p, __ATOMIC_RELAXED, __HIP_MEMORY_SCOPE_AGENT);
}
__device__ __forceinline__ void st_sc1(uint32* p, uint32 v) {
  __hip_atomic_store(p, v, __ATOMIC_RELAXED, __HIP_MEMORY_SCOPE_AGENT);
}
__device__ __forceinline__ void st_sc1_u64(ull* p, ull v) {
  __hip_atomic_store(p, v, __ATOMIC_RELAXED, __HIP_MEMORY_SCOPE_AGENT);
}
__device__ __forceinline__ ull ld_sc1_u64(const ull* p) {
  return __hip_atomic_load((ull*)p, __ATOMIC_RELAXED, __HIP_MEMORY_SCOPE_AGENT);
}

// L1-invalidate (vector cache only) — the gfx94x workgroup-acquire cache op.
__device__ __forceinline__ void l1_inv() {
  asm volatile("buffer_inv sc0\n\ts_waitcnt vmcnt(0)" ::: "memory");
}

__device__ __forceinline__ void wave_poll_sc1(uint32* fl, uint32 tgt) {
  int it = 0;
  for (;;) {
    uint32 v = ld_sc1(fl);
    if (__all((int)(v >= tgt))) break;
    __builtin_amdgcn_s_sleep(1);
    if (++it > 60000) break;   // bounded: wrong beats hang
  }
  asm volatile("" ::: "memory");
}
// fast poll: L1-inv + plain load (hits XCD-shared L2)
__device__ __forceinline__ void wave_poll_fast(const uint32* fl, uint32 tgt) {
  int it = 0;
  for (;;) {
    l1_inv();
    uint32 v = *(const volatile uint32*)fl;
    if (__all((int)(v >= tgt))) break;
    if (++it > 60000) break;
  }
  asm volatile("" ::: "memory");
}

__device__ __forceinline__ void ds_stage(ushort_t* dst, int tid, const ull* v) {
#pragma unroll
  for (int q = 0; q < 8; ++q) {
    int idx = q * 256 + tid;
    int r = idx >> 7, inner = idx & 127;
    *(ull*)&dst[(r * 512 + inner * 4) ^ ((r & 7) << 3)] = v[q];
  }
}

__device__ __forceinline__ void load_sc1_8(const ull* src, int tid, ull* v) {
#pragma unroll
  for (int q = 0; q < 8; ++q) v[q] = ld_sc1_u64(src + q * 256 + tid);
}
__device__ __forceinline__ void load_fast_8(const ull* src, int tid, ull* v) {
  l1_inv();
#pragma unroll
  for (int q = 0; q < 8; ++q) v[q] = *(const volatile ull*)(src + q * 256 + tid);
}

__global__ void __launch_bounds__(256, 1)
lstm_fused(const float* __restrict__ x,
           const float* __restrict__ w_ih0, const float* __restrict__ w_hh0,
           const float* __restrict__ b0,
           const float* __restrict__ w_ih1, const float* __restrict__ w_hh1,
           const float* __restrict__ b1,
           float* __restrict__ out,
           uint32* cnt0F, uint32* cnt1F, uint32* consF,
           uint32* h0locF, uint32* h1locF, uint32* voteWs, uint32* probe,
           ushort_t* ring, ushort_t* h1buf, ushort_t* h0loc, ushort_t* h1loc)
{
  const int b     = (int)blockIdx.x;
  const int g     = b & 7;        // group = (layer,bt); one XCD if round-robin holds
  const int layer = g >> 2;
  const int bt    = g & 3;
  const int ct    = b >> 3;       // 0..31
  const int tid   = (int)threadIdx.x;
  const int wv    = tid >> 6;
  const int lane  = tid & 63;
  const int lr    = lane & 15;
  const int lg    = lane >> 4;

  __shared__ __align__(16) ushort_t Is[16 * 512];
  __shared__ __align__(16) ushort_t Hs[16 * 512];
  __shared__ float gates[4][16][16];
  __shared__ int fastLds;

  uint32* grpXcdMask = voteWs;        // [8]
  uint32* grpRep     = voteWs + 8;    // [8]
  uint32* grpBad     = voteWs + 16;   // [8]
  uint32* arrCnt     = voteWs + 24;   // [1]
  uint32* xcdAll     = voteWs + 25;   // [1]

  // ---------- one-time: marker + vote round 1 ----------
  if (tid == 0) {
    uint32 xcd;
    asm volatile("s_getreg_b32 %0, hwreg(HW_REG_XCC_ID, 0, 4)" : "=s"(xcd));
    xcd &= 15u;
    *(volatile uint32*)(probe + g * 32 + ct) = 0xA5000000u | (uint32)b;  // fast-path store mechanism
    asm volatile("s_waitcnt vmcnt(0)" ::: "memory");
    __hip_atomic_fetch_or(grpXcdMask + g, 1u << (xcd & 31u), __ATOMIC_RELAXED, __HIP_MEMORY_SCOPE_AGENT);
    __hip_atomic_fetch_or(xcdAll, 1u << (xcd & 31u), __ATOMIC_RELAXED, __HIP_MEMORY_SCOPE_AGENT);
    __hip_atomic_fetch_add(arrCnt, 1u, __ATOMIC_RELAXED, __HIP_MEMORY_SCOPE_AGENT);
    int it = 0;
    while (ld_sc1(arrCnt) < 256u) { __builtin_amdgcn_s_sleep(8); if (++it > 5000000) break; }
  }
  __syncthreads();

  // ---------- one-time: empirical coherence probe (fast-path load mechanism) ----------
  int probeOk = 1;
  if (wv == 0) {
    int seen = (lane < 32) ? 0 : 1;
    const uint32 expect = 0xA5000000u | (uint32)((lane & 31) * 8 + g);
    for (int it = 0; it < 4000 && !seen; ++it) {
      l1_inv();
      uint32 v = *(volatile uint32*)(probe + g * 32 + (lane & 31));
      if (v == expect) seen = 1;
    }
    probeOk = __all(seen);
  }
  if (tid == 0) {
    if (!probeOk) __hip_atomic_fetch_or(grpBad + g, 1u, __ATOMIC_RELAXED, __HIP_MEMORY_SCOPE_AGENT);
    __hip_atomic_fetch_add(grpRep + g, 1u, __ATOMIC_RELAXED, __HIP_MEMORY_SCOPE_AGENT);
    int it = 0;
    while (ld_sc1(grpRep + g) < 32u) { __builtin_amdgcn_s_sleep(8); if (++it > 5000000) break; }
    uint32 bad = ld_sc1(grpBad + g);
    uint32 gm  = ld_sc1(grpXcdMask + g);
    uint32 am  = ld_sc1(xcdAll);
    fastLds = (bad == 0u && __popc(gm) == 1 && __popc(am) >= 2) ? 1 : 0;
  }

  const int NI  = layer ? 16 : 8;
  const int Din = layer ? HDIM : DDIM;
  const float* wih = layer ? w_ih1 : w_ih0;
  const float* whh = layer ? w_hh1 : w_hh0;
  const float* bb  = layer ? b1 : b0;
  const int grow = wv * HDIM + ct * 16 + lr;

  short8 wf[32];
#pragma unroll
  for (int kf = 0; kf < 32; ++kf) wf[kf] = (short8)((short)0);
#pragma unroll
  for (int kf = 0; kf < 32; ++kf) {
    if (kf < NI + 16) {
      const float* src;
      if (kf < NI) src = wih + (size_t)grow * Din + (size_t)kf * 32 + lg * 8;
      else         src = whh + (size_t)grow * HDIM + (size_t)(kf - NI) * 32 + lg * 8;
      float4 a = *(const float4*)(src);
      float4 bq = *(const float4*)(src + 4);
      wf[kf] = pack8(a, bq);
    }
  }
  const float bias = bb[grow];

  __syncthreads();
  const bool fast = (bool)fastLds;

  const ull* ring_u  = (const ull*)ring;
  const ull* h1buf_u = (const ull*)h1buf;
  const ull* h0loc_u = (const ull*)h0loc;
  const ull* h1loc_u = (const ull*)h1loc;

  float c4[4] = {0.f, 0.f, 0.f, 0.f};       // wave0 only: 4 cell states
  float4 xp0, xp1, xp2, xp3;                 // layer0: x prefetch regs
  const int xr = tid >> 4, xc = (tid & 15) * 16, xsw = (xr & 7) << 3;

  if (layer == 0) {   // prefetch x[0]
    const float4* xv = (const float4*)(x + (size_t)(bt * 16 + xr) * (TDIM * DDIM) + xc);
    xp0 = xv[0]; xp1 = xv[1]; xp2 = xv[2]; xp3 = xv[3];
  }

  for (int t = 0; t < TDIM; ++t) {
    // ================= phase A: polls =================
    if (layer == 0) {
      if (wv == 0) {
        if (fast) {
          if (t > 0) {   // deferred ring flag for y0[t-1] (stores are ~1 step old)
            asm volatile("s_waitcnt vmcnt(0)" ::: "memory");
            if (lane == 0) st_sc1(cnt0F + bt * 32 + ct, (uint32)t);
          }
          if (t > 0) wave_poll_fast(h0locF + bt * 32 + (lane & 31), (uint32)t);
        } else {
          if (t > 0) wave_poll_sc1(cnt0F + bt * 32 + (lane & 31), (uint32)t);
        }
      } else if (wv == 1) {
        if (t >= RING) wave_poll_sc1(consF + bt * 32 + (lane & 31), (uint32)(t - RING + 1));
      }
    } else {
      if (wv == 0) {
        if (t > 0) {
          if (fast) wave_poll_fast(h1locF + bt * 32 + (lane & 31), (uint32)t);
          else      wave_poll_sc1(cnt1F + bt * 32 + (lane & 31), (uint32)t);
        }
      } else if (wv == 1) {
        wave_poll_sc1(cnt0F + bt * 32 + (lane & 31), (uint32)(t + 1));
      }
    }
    __syncthreads();

    // ================= phase B: stage =================
    if (layer == 0) {
      *(short8*)&Is[(xr * 512 + xc) ^ xsw]     = pack8(xp0, xp1);
      *(short8*)&Is[(xr * 512 + xc + 8) ^ xsw] = pack8(xp2, xp3);
      if (t > 0) {
        ull hv[8];
        if (fast) load_fast_8(h0loc_u + (size_t)bt * 4096 + (size_t)((t - 1) & 1) * 2048, tid, hv);
        else      load_sc1_8(ring_u + (size_t)((t - 1) & (RING - 1)) * 8192 + (size_t)bt * 2048, tid, hv);
        ds_stage(Hs, tid, hv);
      }
    } else {
      ull rv[8], hv[8];
      load_sc1_8(ring_u + (size_t)(t & (RING - 1)) * 8192 + (size_t)bt * 2048, tid, rv);
      if (t > 0) {
        if (fast) load_fast_8(h1loc_u + (size_t)bt * 4096 + (size_t)((t - 1) & 1) * 2048, tid, hv);
        else      load_sc1_8(h1buf_u + (size_t)((t - 1) & 1) * 8192 + (size_t)bt * 2048, tid, hv);
      }
      ds_stage(Is, tid, rv);
      if (t > 0) ds_stage(Hs, tid, hv);
    }
    __syncthreads();
    if (layer == 1 && tid == 0)
      st_sc1(consF + bt * 32 + ct, (uint32)(t + 1));   // ring slot consumed

    // ================= phase C: MFMA + gates =================
    f32x4 acc0 = {0.f, 0.f, 0.f, 0.f}, acc1 = {0.f, 0.f, 0.f, 0.f};
    const int fb  = lr * 512 + lg * 8;
    const int fsw = (lr & 7) << 3;
#pragma unroll
    for (int kf = 0; kf < 16; ++kf) {
      if (kf < NI) {
        const short8 af = *(const short8*)&Is[(fb + kf * 32) ^ fsw];
        if (kf & 1) acc1 = __builtin_amdgcn_mfma_f32_16x16x32_bf16(af, wf[kf], acc1, 0, 0, 0);
        else        acc0 = __builtin_amdgcn_mfma_f32_16x16x32_bf16(af, wf[kf], acc0, 0, 0, 0);
      }
    }
    if (t > 0) {
#pragma unroll
      for (int kf = 0; kf < 16; ++kf) {
        const short8 af = *(const short8*)&Hs[(fb + kf * 32) ^ fsw];
        if (kf & 1) acc1 = __builtin_amdgcn_mfma_f32_16x16x32_bf16(af, wf[NI + kf], acc1, 0, 0, 0);
        else        acc0 = __builtin_amdgcn_mfma_f32_16x16x32_bf16(af, wf[NI + kf], acc0, 0, 0, 0);
      }
    }
#pragma unroll
    for (int i = 0; i < 4; ++i) {
      float v = acc0[i] + acc1[i] + bias;
      float a = (wv < 3) ? sigm(v) : tanh_fast(v);
      gates[wv][lg * 4 + i][lr] = a;
    }
    __syncthreads();

    // ================= phase D/E =================
    if (layer == 0 && wv != 0 && t + 1 < TDIM) {   // x prefetch during pointwise window
      const float4* xv = (const float4*)(x + (size_t)(bt * 16 + xr) * (TDIM * DDIM)
                                           + (size_t)(t + 1) * DDIM + xc);
      xp0 = xv[0]; xp1 = xv[1]; xp2 = xv[2]; xp3 = xv[3];
    }
    if (wv == 0) {
      const int r  = lane >> 2;
      const int cg = lane & 3;
      f32x4 gi = *(const f32x4*)&gates[0][r][cg * 4];
      f32x4 gf = *(const f32x4*)&gates[1][r][cg * 4];
      f32x4 go = *(const f32x4*)&gates[2][r][cg * 4];
      f32x4 gg = *(const f32x4*)&gates[3][r][cg * 4];
      f32x4 nh4, nc4;
#pragma unroll
      for (int k = 0; k < 4; ++k) {
        float nc = gf[k] * c4[k] + gi[k] * gg[k];
        float nh = go[k] * tanh_fast(nc);     // h uses UNCLIPPED c
        nc = fminf(fmaxf(nc, -50.f), 50.f);
        nh = fminf(fmaxf(nh, -50.f), 50.f);
        c4[k] = nc; nh4[k] = nh; nc4[k] = nc;
      }
      const ull hv = pack4bf(nh4);
      if (fast) {
        ull* dst = (ull*)((layer == 0 ? h0loc_u : h1loc_u)
                          + (size_t)bt * 4096 + (size_t)(t & 1) * 2048 + r * 128 + ct * 4 + cg);
        *dst = hv;                                   // plain: write-through to XCD L2
        asm volatile("s_waitcnt vmcnt(0)" ::: "memory");
        if (lane == 0)
          *(volatile uint32*)((layer == 0 ? h0locF : h1locF) + bt * 32 + ct) = (uint32)(t + 1);
        if (layer == 0) {                            // ring copy for L1, flag deferred
          st_sc1_u64((ull*)(ring_u + (size_t)(t & (RING - 1)) * 8192
                            + (size_t)(bt * 16 + r) * 128 + ct * 4 + cg), hv);
        }
      } else {
        ull* dst;
        if (layer == 0)
          dst = (ull*)(ring_u + (size_t)(t & (RING - 1)) * 8192
                       + (size_t)(bt * 16 + r) * 128 + ct * 4 + cg);
        else
          dst = (ull*)(h1buf_u + (size_t)(t & 1) * 8192
                       + (size_t)(bt * 16 + r) * 128 + ct * 4 + cg);
        st_sc1_u64(dst, hv);
        asm volatile("s_waitcnt vmcnt(0)" ::: "memory");
        if (lane == 0) st_sc1((layer == 0 ? cnt0F : cnt1F) + bt * 32 + ct, (uint32)(t + 1));
      }
      if (layer == 1)
        *(f32x4*)&out[(size_t)(bt * 16 + r) * (TDIM * HDIM) + (size_t)t * HDIM + ct * 16 + cg * 4] = nh4;
      if (t == TDIM - 1) {
        const size_t OH = (size_t)BDIM * TDIM * HDIM;
        const size_t OC = OH + 2 * (size_t)BDIM * HDIM;
        *(f32x4*)&out[OH + (size_t)layer * BDIM * HDIM + (size_t)(bt * 16 + r) * HDIM + ct * 16 + cg * 4] = nh4;
        *(f32x4*)&out[OC + (size_t)layer * BDIM * HDIM + (size_t)(bt * 16 + r) * HDIM + ct * 16 + cg * 4] = nc4;
      }
      if (layer == 0 && t + 1 < TDIM) {   // wv0's own x prefetch, after publish
        const float4* xv = (const float4*)(x + (size_t)(bt * 16 + xr) * (TDIM * DDIM)
                                             + (size_t)(t + 1) * DDIM + xc);
        xp0 = xv[0]; xp1 = xv[1]; xp2 = xv[2]; xp3 = xv[3];
      }
    }
  }

  if (fast && layer == 0 && wv == 0) {   // release y0[1023] to layer1
    asm volatile("s_waitcnt vmcnt(0)" ::: "memory");
    if (lane == 0) st_sc1(cnt0F + bt * 32 + ct, (uint32)TDIM);
  }
}

extern "C" void kernel_launch(void* const* d_in, const int* in_sizes, int n_in,
                              void* d_out, int out_size, void* d_ws, size_t ws_size,
                              hipStream_t stream) {
  (void)in_sizes; (void)n_in; (void)out_size; (void)ws_size;
  const float* x     = (const float*)d_in[0];
  const float* w_ih0 = (const float*)d_in[1];
  const float* w_hh0 = (const float*)d_in[2];
  const float* b0    = (const float*)d_in[3];
  const float* w_ih1 = (const float*)d_in[4];
  const float* w_hh1 = (const float*)d_in[5];
  const float* b1    = (const float*)d_in[6];
  float* out = (float*)d_out;

  char* ws = (char*)d_ws;
  uint32* cnt0F  = (uint32*)(ws + 0);      // [4][32]
  uint32* cnt1F  = (uint32*)(ws + 512);    // [4][32]
  uint32* consF  = (uint32*)(ws + 1024);   // [4][32]
  uint32* h0locF = (uint32*)(ws + 1536);   // [4][32]
  uint32* h1locF = (uint32*)(ws + 2048);   // [4][32]
  uint32* voteWs = (uint32*)(ws + 2560);   // masks/counters
  uint32* probe  = (uint32*)(ws + 3072);   // [8][32]
  ushort_t* ring  = (ushort_t*)(ws + 8192);                        // [8][64][512] (512KB)
  ushort_t* h1buf = (ushort_t*)(ws + 8192 + 524288);               // [2][64][512] (128KB)
  ushort_t* h0loc = (ushort_t*)(ws + 8192 + 524288 + 131072);      // [4][2][16][512] (128KB)
  ushort_t* h1loc = (ushort_t*)(ws + 8192 + 524288 + 131072 + 131072);

  hipMemsetAsync(ws, 0, 4096, stream);
  lstm_fused<<<dim3(256), dim3(256), 0, stream>>>(
      x, w_ih0, w_hh0, b0, w_ih1, w_hh1, b1, out,
      cnt0F, cnt1F, consF, h0locF, h1locF, voteWs, probe,
      ring, h1buf, h0loc, h1loc);
}